// Round 1
// baseline (81.240 us; speedup 1.0000x reference)
//
#include <hip/hip_runtime.h>
#include <stdint.h>

#define N 2048
#define F 128
#define UDIM 128

typedef __attribute__((ext_vector_type(8))) __bf16 bf16x8;
typedef __attribute__((ext_vector_type(8))) unsigned short us8;
typedef __attribute__((ext_vector_type(4))) float f32x4;

__device__ __forceinline__ unsigned short f2bf(float f) {
  union { float f; uint32_t u; } v; v.f = f;
  uint32_t u = v.u;
  return (unsigned short)((u + 0x7FFFu + ((u >> 16) & 1u)) >> 16);
}

__device__ __forceinline__ void async_load16(const void* g, void* l) {
  typedef const __attribute__((address_space(1))) uint32_t* gp_t;
  typedef __attribute__((address_space(3))) uint32_t* lp_t;
  __builtin_amdgcn_global_load_lds((gp_t)(uintptr_t)g, (lp_t)(uint32_t)(uintptr_t)l, 16, 0, 0);
}

// ---------------- kernel 1: column-sum partials ----------------
// grid (2, 32, 8), block 256. partial[b][rc][j], rc = 32 chunks of 64 rows.
__global__ __launch_bounds__(256)
void gcn_colsum(const float* __restrict__ A, float* __restrict__ partial) {
  const int b = blockIdx.z;
  const int rc = blockIdx.y;
  const int j = blockIdx.x * 1024 + threadIdx.x * 4;
  const float* ap = A + (size_t)b * N * N + (size_t)rc * 64 * N + j;
  float sx = 0.f, sy = 0.f, sz = 0.f, sw = 0.f;
  #pragma unroll 4
  for (int rr = 0; rr < 64; ++rr) {
    float4 v = *(const float4*)(ap + (size_t)rr * N);
    sx += v.x; sy += v.y; sz += v.z; sw += v.w;
  }
  float4 s; s.x = sx; s.y = sy; s.z = sz; s.w = sw;
  *(float4*)&partial[((size_t)b * 32 + rc) * N + j] = s;
}

// ---------------- kernel 2: finalize k_clean + W transpose (bf16) ----------------
// grid 128: blocks 0..63 finalize kc, 64..127 build WT_bf[u][k].
__global__ __launch_bounds__(256)
void gcn_small(const float* __restrict__ partial, const float* __restrict__ pptr,
               const float* __restrict__ W, float* __restrict__ kcl,
               unsigned short* __restrict__ WTb) {
  const int t = threadIdx.x;
  const int bid = blockIdx.x;
  if (bid < 64) {
    const int idx = bid * 256 + t;          // b*N + j
    const int b = idx >> 11;
    const int j = idx & (N - 1);
    float s = 0.f;
    #pragma unroll 8
    for (int rc = 0; rc < 32; ++rc) s += partial[((size_t)b * 32 + rc) * N + j];
    const float sp = 1.0f / (1.0f + __expf(-pptr[0]));
    const float k = sp + (1.0f - sp) * s;
    float rv = rsqrtf(sqrtf(k));            // k^(-0.25)
    if (isinf(rv)) rv = 0.f;
    kcl[idx] = rv;
  } else {
    const int idx = (bid - 64) * 256 + t;   // k_*128 + u  (coalesced W read)
    const int k_ = idx >> 7;
    const int u = idx & 127;
    WTb[u * 128 + k_] = f2bf(W[idx]);
  }
}

// ---------------- kernel 3: YT[b,u,i] = kc[b,i] * (X@W)[i,u], computed transposed ----------------
// grid 512 (8 b x 64 i-chunks of 32), block 256 = 4 waves; wave w owns u in [w*32, w*32+32).
__global__ __launch_bounds__(256, 2)
void gcn_xwT(const float* __restrict__ X, const unsigned short* __restrict__ WTb,
             const float* __restrict__ kcl, unsigned short* __restrict__ YT) {
  __shared__ __align__(16) unsigned short Wl[128 * 128];  // [u][k] swizzled, 32 KB
  __shared__ __align__(16) unsigned short Xl[32 * 128];   // [i][k] swizzled, 8 KB

  const int t = threadIdx.x;
  const int lane = t & 63;
  const int wid = t >> 6;
  const int b = blockIdx.x >> 6;
  const int i0 = (blockIdx.x & 63) << 5;

  // stage WT (global_load_lds, linear dest, inverse-swizzled source)
  #pragma unroll
  for (int rnd = 0; rnd < 8; ++rnd) {
    const int u = rnd * 16 + (t >> 4);
    const int c16 = (t & 15) ^ (u & 7);
    async_load16(WTb + u * 128 + c16 * 8, &Wl[rnd * 2048 + (t & ~63) * 8]);
  }
  // stage X tile (reg-staged fp32->bf16, swizzled ds_write)
  {
    const int r = t >> 3;
    const float* xp = X + ((size_t)b * N + i0 + r) * F + (t & 7) * 8;
    #pragma unroll
    for (int h = 0; h < 2; ++h) {
      float4 v0 = *(const float4*)(xp + h * 64);
      float4 v1 = *(const float4*)(xp + h * 64 + 4);
      us8 w;
      w[0] = f2bf(v0.x); w[1] = f2bf(v0.y); w[2] = f2bf(v0.z); w[3] = f2bf(v0.w);
      w[4] = f2bf(v1.x); w[5] = f2bf(v1.y); w[6] = f2bf(v1.z); w[7] = f2bf(v1.w);
      const int slot = (t & 7) + h * 8;
      *(us8*)&Xl[r * 128 + ((slot ^ (r & 7)) * 8)] = w;
    }
  }
  __syncthreads();

  f32x4 acc[2][2];
  #pragma unroll
  for (int a = 0; a < 2; ++a)
    #pragma unroll
    for (int c = 0; c < 2; ++c) { f32x4 z = {0.f, 0.f, 0.f, 0.f}; acc[a][c] = z; }

  const int u0 = wid * 32;
  #pragma unroll
  for (int kc = 0; kc < 4; ++kc) {
    bf16x8 af[2], bfv[2];
    #pragma unroll
    for (int ut = 0; ut < 2; ++ut) {
      const int u = u0 + ut * 16 + (lane & 15);
      const int sl = ((kc * 4 + (lane >> 4)) ^ (u & 7)) * 8;
      af[ut] = *(const bf16x8*)&Wl[u * 128 + sl];
    }
    #pragma unroll
    for (int it = 0; it < 2; ++it) {
      const int rr = it * 16 + (lane & 15);
      const int sl = ((kc * 4 + (lane >> 4)) ^ (rr & 7)) * 8;
      bfv[it] = *(const bf16x8*)&Xl[rr * 128 + sl];
    }
    #pragma unroll
    for (int ut = 0; ut < 2; ++ut)
      #pragma unroll
      for (int it = 0; it < 2; ++it)
        acc[ut][it] = __builtin_amdgcn_mfma_f32_16x16x32_bf16(af[ut], bfv[it], acc[ut][it], 0, 0, 0);
  }

  // epilogue: scale by kc[b,i], write YT[b,u,i] (coalesced in i)
  #pragma unroll
  for (int ut = 0; ut < 2; ++ut) {
    #pragma unroll
    for (int it = 0; it < 2; ++it) {
      const int ic = i0 + it * 16 + (lane & 15);
      const float kv = kcl[b * N + ic];
      #pragma unroll
      for (int rg = 0; rg < 4; ++rg) {
        const int u = u0 + ut * 16 + (lane >> 4) * 4 + rg;
        YT[(size_t)b * UDIM * N + (size_t)u * N + ic] = f2bf(acc[ut][it][rg] * kv);
      }
    }
  }
}

// ---------------- kernel 4: out = relu(kc_i * (A + qs I) @ Y + bias) ----------------
// grid 512 (8 b x 64 m-tiles of 32 rows), block 256 = 4 waves (2x2).
__global__ __launch_bounds__(256, 2)
void gcn_gemm(const float* __restrict__ A, const unsigned short* __restrict__ YT,
              const float* __restrict__ kcl, const float* __restrict__ bias,
              const float* __restrict__ qptr, float* __restrict__ out) {
  __shared__ __align__(16) unsigned short Abuf[2][32 * 64];   // 4 KB each, swizzled
  __shared__ __align__(16) unsigned short Ybuf[2][128 * 64];  // 16 KB each, swizzled

  const int t = threadIdx.x;
  const int lane = t & 63;
  const int wid = t >> 6;
  const int wr = wid >> 1;
  const int wc = wid & 1;

  const int bid = blockIdx.x;
  const int b = bid >> 6;
  const int i0 = (bid & 63) << 5;

  const float qs = 1.0f / (1.0f + __expf(-qptr[0]));

  const int r = t >> 3;        // A-staging row within tile (0..31)
  const int c8 = t & 7;        // A-staging 8-float column chunk
  const int grow = i0 + r;     // global row (for diagonal term)
  const float* Ab = A + (size_t)b * N * N + (size_t)grow * N + c8 * 8;
  const unsigned short* YTb = YT + (size_t)b * UDIM * N;

  const int a_woff = r * 64 + ((c8 ^ (r & 7)) * 8);
  const int y_u = t >> 3;               // + rnd*32
  const int y_wavebase = (t & ~63) * 8; // ushort offset of wave's 1KB slice

  f32x4 acc[4];
  #pragma unroll
  for (int i = 0; i < 4; ++i) { f32x4 z = {0.f, 0.f, 0.f, 0.f}; acc[i] = z; }

  float areg[8];

  // prologue: stage k-tile 0 into buffer 0
  {
    #pragma unroll
    for (int rnd = 0; rnd < 4; ++rnd) {
      const int u = rnd * 32 + y_u;
      const int c16 = (t & 7) ^ (u & 7);
      async_load16(YTb + (size_t)u * N + c16 * 8, &Ybuf[0][rnd * 2048 + y_wavebase]);
    }
    float4 v0 = *(const float4*)(Ab);
    float4 v1 = *(const float4*)(Ab + 4);
    areg[0] = v0.x; areg[1] = v0.y; areg[2] = v0.z; areg[3] = v0.w;
    areg[4] = v1.x; areg[5] = v1.y; areg[6] = v1.z; areg[7] = v1.w;
    const int dj = grow - c8 * 8;
    if (0 <= dj && dj < 8) areg[dj] += qs;   // fold qs*I into A tile
    us8 w;
    #pragma unroll
    for (int e = 0; e < 8; ++e) w[e] = f2bf(areg[e]);
    *(us8*)&Abuf[0][a_woff] = w;
    __syncthreads();
  }

  for (int kt = 0; kt < 32; ++kt) {
    const int cur = kt & 1;
    const int nxt = cur ^ 1;
    const int k0n = (kt + 1) * 64;
    const bool has_next = (kt < 31);

    if (has_next) {
      #pragma unroll
      for (int rnd = 0; rnd < 4; ++rnd) {
        const int u = rnd * 32 + y_u;
        const int c16 = (t & 7) ^ (u & 7);
        async_load16(YTb + (size_t)u * N + k0n + c16 * 8, &Ybuf[nxt][rnd * 2048 + y_wavebase]);
      }
      float4 v0 = *(const float4*)(Ab + k0n);
      float4 v1 = *(const float4*)(Ab + k0n + 4);
      areg[0] = v0.x; areg[1] = v0.y; areg[2] = v0.z; areg[3] = v0.w;
      areg[4] = v1.x; areg[5] = v1.y; areg[6] = v1.z; areg[7] = v1.w;
    }

    // compute on current buffer
    #pragma unroll
    for (int kk = 0; kk < 2; ++kk) {
      const int ar = 16 * wr + (lane & 15);
      const int as = ((kk * 4 + (lane >> 4)) ^ (ar & 7)) * 8;
      bf16x8 af = *(const bf16x8*)&Abuf[cur][ar * 64 + as];
      #pragma unroll
      for (int ut = 0; ut < 4; ++ut) {
        const int u = 64 * wc + ut * 16 + (lane & 15);
        const int bs = ((kk * 4 + (lane >> 4)) ^ (u & 7)) * 8;
        bf16x8 bfv = *(const bf16x8*)&Ybuf[cur][u * 64 + bs];
        acc[ut] = __builtin_amdgcn_mfma_f32_16x16x32_bf16(af, bfv, acc[ut], 0, 0, 0);
      }
    }

    if (has_next) {
      const int dj = grow - (k0n + c8 * 8);
      if (0 <= dj && dj < 8) areg[dj] += qs;
      us8 w;
      #pragma unroll
      for (int e = 0; e < 8; ++e) w[e] = f2bf(areg[e]);
      *(us8*)&Abuf[nxt][a_woff] = w;
    }
    __syncthreads();
  }

  // epilogue: row scale + bias + relu
  const int irow = i0 + 16 * wr + (lane >> 4) * 4;
  #pragma unroll
  for (int ut = 0; ut < 4; ++ut) {
    const int u = 64 * wc + ut * 16 + (lane & 15);
    const float bv = bias[u];
    #pragma unroll
    for (int rg = 0; rg < 4; ++rg) {
      const int i = irow + rg;
      const float kv = kcl[b * N + i];
      float vv = kv * acc[ut][rg] + bv;
      out[((size_t)b * N + i) * UDIM + u] = vv > 0.f ? vv : 0.f;
    }
  }
}

extern "C" void kernel_launch(void* const* d_in, const int* in_sizes, int n_in,
                              void* d_out, int out_size, void* d_ws, size_t ws_size,
                              hipStream_t stream) {
  (void)in_sizes; (void)n_in; (void)out_size; (void)ws_size;
  const float* A    = (const float*)d_in[0];
  const float* X    = (const float*)d_in[1];
  const float* W    = (const float*)d_in[2];
  const float* bias = (const float*)d_in[3];
  const float* p    = (const float*)d_in[4];
  const float* q    = (const float*)d_in[5];
  float* out = (float*)d_out;

  char* ws = (char*)d_ws;
  float* partial      = (float*)ws;                                  // 8*32*2048*4 = 2 MB
  float* kcl          = (float*)(ws + 2097152);                      // 64 KB
  unsigned short* WTb = (unsigned short*)(ws + 2097152 + 65536);     // 32 KB
  unsigned short* YT  = (unsigned short*)(ws + 2097152 + 65536 + 32768); // 4 MB

  gcn_colsum<<<dim3(2, 32, 8), dim3(256), 0, stream>>>(A, partial);
  gcn_small<<<dim3(128), dim3(256), 0, stream>>>(partial, p, W, kcl, WTb);
  gcn_xwT<<<dim3(512), dim3(256), 0, stream>>>(X, WTb, kcl, YT);
  gcn_gemm<<<dim3(512), dim3(256), 0, stream>>>(A, YT, kcl, bias, q, out);
}

// Round 2
// 65.566 us; speedup vs baseline: 1.2391x; 1.2391x over previous
//
#include <hip/hip_runtime.h>
#include <stdint.h>

#define N 2048
#define F 128
#define UDIM 128

typedef __attribute__((ext_vector_type(8))) __bf16 bf16x8;
typedef __attribute__((ext_vector_type(8))) unsigned short us8;
typedef __attribute__((ext_vector_type(4))) float f32x4;

__device__ __forceinline__ unsigned short f2bf(float f) {
  union { float f; uint32_t u; } v; v.f = f;
  uint32_t u = v.u;
  return (unsigned short)((u + 0x7FFFu + ((u >> 16) & 1u)) >> 16);
}

__device__ __forceinline__ void async_load16(const void* g, void* l) {
  typedef const __attribute__((address_space(1))) uint32_t* gp_t;
  typedef __attribute__((address_space(3))) uint32_t* lp_t;
  __builtin_amdgcn_global_load_lds((gp_t)(uintptr_t)g, (lp_t)(uint32_t)(uintptr_t)l, 16, 0, 0);
}

// ---------------- kernel 1: column-sum partials + A -> bf16 (with qs*I folded) ----------------
// grid (2, 32, 8), block 256. partial[b][rc][j], rc = 32 chunks of 64 rows.
// Also writes Abf[b][i][j] = bf16(A[b][i][j] + qs*(i==j)). Colsum uses raw A (pre-diagonal).
__global__ __launch_bounds__(256)
void gcn_colsum_conv(const float* __restrict__ A, const float* __restrict__ qptr,
                     float* __restrict__ partial, unsigned short* __restrict__ Abf) {
  const int b = blockIdx.z;
  const int rc = blockIdx.y;
  const int j = blockIdx.x * 1024 + threadIdx.x * 4;
  const float qs = 1.0f / (1.0f + __expf(-qptr[0]));
  const size_t base = (size_t)b * N * N + (size_t)rc * 64 * N + j;
  const float* ap = A + base;
  unsigned short* op = Abf + base;
  const int grow0 = rc * 64;
  float s0 = 0.f, s1 = 0.f, s2 = 0.f, s3 = 0.f;
  #pragma unroll 4
  for (int rr = 0; rr < 64; ++rr) {
    float4 v = *(const float4*)(ap + (size_t)rr * N);
    s0 += v.x; s1 += v.y; s2 += v.z; s3 += v.w;
    const int dj = grow0 + rr - j;           // diagonal position within this thread's 4 cols
    if (dj == 0) v.x += qs;
    else if (dj == 1) v.y += qs;
    else if (dj == 2) v.z += qs;
    else if (dj == 3) v.w += qs;
    ushort4 o;
    o.x = f2bf(v.x); o.y = f2bf(v.y); o.z = f2bf(v.z); o.w = f2bf(v.w);
    *(ushort4*)(op + (size_t)rr * N) = o;
  }
  float4 s; s.x = s0; s.y = s1; s.z = s2; s.w = s3;
  *(float4*)&partial[((size_t)b * 32 + rc) * N + j] = s;
}

// ---------------- kernel 2: finalize k_clean + W transpose (bf16) ----------------
__global__ __launch_bounds__(256)
void gcn_small(const float* __restrict__ partial, const float* __restrict__ pptr,
               const float* __restrict__ W, float* __restrict__ kcl,
               unsigned short* __restrict__ WTb) {
  const int t = threadIdx.x;
  const int bid = blockIdx.x;
  if (bid < 64) {
    const int idx = bid * 256 + t;          // b*N + j
    const int b = idx >> 11;
    const int j = idx & (N - 1);
    float s = 0.f;
    #pragma unroll 8
    for (int rc = 0; rc < 32; ++rc) s += partial[((size_t)b * 32 + rc) * N + j];
    const float sp = 1.0f / (1.0f + __expf(-pptr[0]));
    const float k = sp + (1.0f - sp) * s;
    float rv = rsqrtf(sqrtf(k));            // k^(-0.25)
    if (isinf(rv)) rv = 0.f;
    kcl[idx] = rv;
  } else {
    const int idx = (bid - 64) * 256 + t;   // k_*128 + u  (coalesced W read)
    const int k_ = idx >> 7;
    const int u = idx & 127;
    WTb[u * 128 + k_] = f2bf(W[idx]);
  }
}

// ---------------- kernel 3: YT[b,u,i] = kc[b,i] * (X@W)[i,u], computed transposed ----------------
// grid 512 (8 b x 64 i-chunks of 32), block 256 = 4 waves; wave w owns u in [w*32, w*32+32).
__global__ __launch_bounds__(256, 2)
void gcn_xwT(const float* __restrict__ X, const unsigned short* __restrict__ WTb,
             const float* __restrict__ kcl, unsigned short* __restrict__ YT) {
  __shared__ __align__(16) unsigned short Wl[128 * 128];  // [u][k] swizzled, 32 KB
  __shared__ __align__(16) unsigned short Xl[32 * 128];   // [i][k] swizzled, 8 KB

  const int t = threadIdx.x;
  const int lane = t & 63;
  const int wid = t >> 6;
  const int b = blockIdx.x >> 6;
  const int i0 = (blockIdx.x & 63) << 5;

  // stage WT (global_load_lds, linear dest, inverse-swizzled source)
  #pragma unroll
  for (int rnd = 0; rnd < 8; ++rnd) {
    const int u = rnd * 16 + (t >> 4);
    const int c16 = (t & 15) ^ (u & 7);
    async_load16(WTb + u * 128 + c16 * 8, &Wl[rnd * 2048 + (t & ~63) * 8]);
  }
  // stage X tile (reg-staged fp32->bf16, swizzled ds_write)
  {
    const int r = t >> 3;
    const float* xp = X + ((size_t)b * N + i0 + r) * F + (t & 7) * 8;
    #pragma unroll
    for (int h = 0; h < 2; ++h) {
      float4 v0 = *(const float4*)(xp + h * 64);
      float4 v1 = *(const float4*)(xp + h * 64 + 4);
      us8 w;
      w[0] = f2bf(v0.x); w[1] = f2bf(v0.y); w[2] = f2bf(v0.z); w[3] = f2bf(v0.w);
      w[4] = f2bf(v1.x); w[5] = f2bf(v1.y); w[6] = f2bf(v1.z); w[7] = f2bf(v1.w);
      const int slot = (t & 7) + h * 8;
      *(us8*)&Xl[r * 128 + ((slot ^ (r & 7)) * 8)] = w;
    }
  }
  __syncthreads();

  f32x4 acc[2][2];
  #pragma unroll
  for (int a = 0; a < 2; ++a)
    #pragma unroll
    for (int c = 0; c < 2; ++c) { f32x4 z = {0.f, 0.f, 0.f, 0.f}; acc[a][c] = z; }

  const int u0 = wid * 32;
  #pragma unroll
  for (int kc = 0; kc < 4; ++kc) {
    bf16x8 af[2], bfv[2];
    #pragma unroll
    for (int ut = 0; ut < 2; ++ut) {
      const int u = u0 + ut * 16 + (lane & 15);
      const int sl = ((kc * 4 + (lane >> 4)) ^ (u & 7)) * 8;
      af[ut] = *(const bf16x8*)&Wl[u * 128 + sl];
    }
    #pragma unroll
    for (int it = 0; it < 2; ++it) {
      const int rr = it * 16 + (lane & 15);
      const int sl = ((kc * 4 + (lane >> 4)) ^ (rr & 7)) * 8;
      bfv[it] = *(const bf16x8*)&Xl[rr * 128 + sl];
    }
    #pragma unroll
    for (int ut = 0; ut < 2; ++ut)
      #pragma unroll
      for (int it = 0; it < 2; ++it)
        acc[ut][it] = __builtin_amdgcn_mfma_f32_16x16x32_bf16(af[ut], bfv[it], acc[ut][it], 0, 0, 0);
  }

  // epilogue: scale by kc[b,i], write YT[b,u,i] (coalesced in i)
  #pragma unroll
  for (int ut = 0; ut < 2; ++ut) {
    #pragma unroll
    for (int it = 0; it < 2; ++it) {
      const int ic = i0 + it * 16 + (lane & 15);
      const float kv = kcl[b * N + ic];
      #pragma unroll
      for (int rg = 0; rg < 4; ++rg) {
        const int u = u0 + ut * 16 + (lane >> 4) * 4 + rg;
        YT[(size_t)b * UDIM * N + (size_t)u * N + ic] = f2bf(acc[ut][it][rg] * kv);
      }
    }
  }
}

// ---------------- kernel 4: out = relu(kc_i * Abf @ Y + bias) ----------------
// grid 512 (8 b x 64 m-tiles of 32 rows), block 256 = 4 waves (2x2).
// Abf is bf16 with qs*I already folded; kc_j already folded into YT.
__global__ __launch_bounds__(256, 2)
void gcn_gemm(const unsigned short* __restrict__ Abf, const unsigned short* __restrict__ YT,
              const float* __restrict__ kcl, const float* __restrict__ bias,
              float* __restrict__ out) {
  __shared__ __align__(16) unsigned short Abuf[2][32 * 64];   // 4 KB each, swizzled
  __shared__ __align__(16) unsigned short Ybuf[2][128 * 64];  // 16 KB each, swizzled

  const int t = threadIdx.x;
  const int lane = t & 63;
  const int wid = t >> 6;
  const int wr = wid >> 1;
  const int wc = wid & 1;

  const int bid = blockIdx.x;
  const int b = bid >> 6;
  const int i0 = (bid & 63) << 5;

  const int r = t >> 3;        // A-staging row within tile (0..31)
  const int c8 = t & 7;        // A-staging 8-elem column chunk
  const unsigned short* Ab = Abf + (size_t)b * N * N + (size_t)(i0 + r) * N + ((c8 ^ (r & 7)) * 8);
  const unsigned short* YTb = YT + (size_t)b * UDIM * N;

  const int a_wavebase = (t & ~63) * 8;   // ushort offset of wave's 1KB LDS slice
  const int y_u = t >> 3;                 // + rnd*32
  const int y_wavebase = (t & ~63) * 8;

  f32x4 acc[4];
  #pragma unroll
  for (int i = 0; i < 4; ++i) { f32x4 z = {0.f, 0.f, 0.f, 0.f}; acc[i] = z; }

  // prologue: stage k-tile 0 into buffer 0
  {
    #pragma unroll
    for (int rnd = 0; rnd < 4; ++rnd) {
      const int u = rnd * 32 + y_u;
      const int c16 = (t & 7) ^ (u & 7);
      async_load16(YTb + (size_t)u * N + c16 * 8, &Ybuf[0][rnd * 2048 + y_wavebase]);
    }
    async_load16(Ab, &Abuf[0][a_wavebase]);
    __syncthreads();
  }

  for (int kt = 0; kt < 32; ++kt) {
    const int cur = kt & 1;
    const int nxt = cur ^ 1;
    const int k0n = (kt + 1) * 64;
    const bool has_next = (kt < 31);

    if (has_next) {
      #pragma unroll
      for (int rnd = 0; rnd < 4; ++rnd) {
        const int u = rnd * 32 + y_u;
        const int c16 = (t & 7) ^ (u & 7);
        async_load16(YTb + (size_t)u * N + k0n + c16 * 8, &Ybuf[nxt][rnd * 2048 + y_wavebase]);
      }
      async_load16(Ab + k0n, &Abuf[nxt][a_wavebase]);
    }

    // compute on current buffer
    #pragma unroll
    for (int kk = 0; kk < 2; ++kk) {
      const int ar = 16 * wr + (lane & 15);
      const int as = ((kk * 4 + (lane >> 4)) ^ (ar & 7)) * 8;
      bf16x8 af = *(const bf16x8*)&Abuf[cur][ar * 64 + as];
      #pragma unroll
      for (int ut = 0; ut < 4; ++ut) {
        const int u = 64 * wc + ut * 16 + (lane & 15);
        const int bs = ((kk * 4 + (lane >> 4)) ^ (u & 7)) * 8;
        bf16x8 bfv = *(const bf16x8*)&Ybuf[cur][u * 64 + bs];
        acc[ut] = __builtin_amdgcn_mfma_f32_16x16x32_bf16(af, bfv, acc[ut], 0, 0, 0);
      }
    }
    __syncthreads();
  }

  // epilogue: row scale + bias + relu
  const int irow = i0 + 16 * wr + (lane >> 4) * 4;
  #pragma unroll
  for (int ut = 0; ut < 4; ++ut) {
    const int u = 64 * wc + ut * 16 + (lane & 15);
    const float bv = bias[u];
    #pragma unroll
    for (int rg = 0; rg < 4; ++rg) {
      const int i = irow + rg;
      const float kv = kcl[b * N + i];
      float vv = kv * acc[ut][rg] + bv;
      out[((size_t)b * N + i) * UDIM + u] = vv > 0.f ? vv : 0.f;
    }
  }
}

extern "C" void kernel_launch(void* const* d_in, const int* in_sizes, int n_in,
                              void* d_out, int out_size, void* d_ws, size_t ws_size,
                              hipStream_t stream) {
  (void)in_sizes; (void)n_in; (void)out_size; (void)ws_size;
  const float* A    = (const float*)d_in[0];
  const float* X    = (const float*)d_in[1];
  const float* W    = (const float*)d_in[2];
  const float* bias = (const float*)d_in[3];
  const float* p    = (const float*)d_in[4];
  const float* q    = (const float*)d_in[5];
  float* out = (float*)d_out;

  char* ws = (char*)d_ws;
  float* partial      = (float*)ws;                                   // 2 MB
  float* kcl          = (float*)(ws + 2097152);                       // 64 KB
  unsigned short* WTb = (unsigned short*)(ws + 2097152 + 65536);      // 32 KB
  unsigned short* YT  = (unsigned short*)(ws + 2195456);              // 4 MB
  unsigned short* Abf = (unsigned short*)(ws + 2195456 + 4194304);    // 64 MB

  gcn_colsum_conv<<<dim3(2, 32, 8), dim3(256), 0, stream>>>(A, q, partial, Abf);
  gcn_small<<<dim3(128), dim3(256), 0, stream>>>(partial, p, W, kcl, WTb);
  gcn_xwT<<<dim3(512), dim3(256), 0, stream>>>(X, WTb, kcl, YT);
  gcn_gemm<<<dim3(512), dim3(256), 0, stream>>>(Abf, YT, kcl, bias, out);
}

// Round 3
// 63.107 us; speedup vs baseline: 1.2873x; 1.0390x over previous
//
#include <hip/hip_runtime.h>
#include <stdint.h>

#define N 2048
#define F 128
#define UDIM 128

typedef __attribute__((ext_vector_type(8))) __bf16 bf16x8;
typedef __attribute__((ext_vector_type(8))) unsigned short us8;
typedef __attribute__((ext_vector_type(4))) float f32x4;

__device__ __forceinline__ unsigned short f2bf(float f) {
  union { float f; uint32_t u; } v; v.f = f;
  uint32_t u = v.u;
  return (unsigned short)((u + 0x7FFFu + ((u >> 16) & 1u)) >> 16);
}

__device__ __forceinline__ void async_load16(const void* g, void* l) {
  typedef const __attribute__((address_space(1))) uint32_t* gp_t;
  typedef __attribute__((address_space(3))) uint32_t* lp_t;
  __builtin_amdgcn_global_load_lds((gp_t)(uintptr_t)g, (lp_t)(uint32_t)(uintptr_t)l, 16, 0, 0);
}

// ---------------- kernel 1: column-sum partials + A -> bf16 (qs*I folded) + W -> WTb ----------------
// grid (2, 64, 8), block 256, 32 rows per block. partial[b][rc][j].
__global__ __launch_bounds__(256)
void gcn_colsum_conv(const float* __restrict__ A, const float* __restrict__ qptr,
                     const float* __restrict__ W,
                     float* __restrict__ partial, unsigned short* __restrict__ Abf,
                     unsigned short* __restrict__ WTb) {
  const int b = blockIdx.z;
  const int rc = blockIdx.y;
  const int j = blockIdx.x * 1024 + threadIdx.x * 4;
  const float qs = 1.0f / (1.0f + __expf(-qptr[0]));
  const size_t base = (size_t)b * N * N + (size_t)rc * 32 * N + j;
  const float* ap = A + base;
  unsigned short* op = Abf + base;
  const int grow0 = rc * 32;
  float s0 = 0.f, s1 = 0.f, s2 = 0.f, s3 = 0.f;
  #pragma unroll 4
  for (int rr = 0; rr < 32; ++rr) {
    float4 v = *(const float4*)(ap + (size_t)rr * N);
    s0 += v.x; s1 += v.y; s2 += v.z; s3 += v.w;
    const int dj = grow0 + rr - j;           // diagonal position within this thread's 4 cols
    if (dj == 0) v.x += qs;
    else if (dj == 1) v.y += qs;
    else if (dj == 2) v.z += qs;
    else if (dj == 3) v.w += qs;
    ushort4 o;
    o.x = f2bf(v.x); o.y = f2bf(v.y); o.z = f2bf(v.z); o.w = f2bf(v.w);
    *(ushort4*)(op + (size_t)rr * N) = o;
  }
  float4 s; s.x = s0; s.y = s1; s.z = s2; s.w = s3;
  *(float4*)&partial[((size_t)b * 64 + rc) * N + j] = s;

  // 2 designated blocks also build WT_bf[u][k] (16384 elems, coalesced W read)
  if (blockIdx.y == 0 && blockIdx.z == 0) {
    #pragma unroll 4
    for (int it = 0; it < 32; ++it) {
      const int flat = it * 512 + blockIdx.x * 256 + threadIdx.x;
      const int k_ = flat >> 7;
      const int u = flat & 127;
      WTb[u * 128 + k_] = f2bf(W[flat]);
    }
  }
}

// ---------------- kernel 2: YT[b,u,i] = kc[b,i]*(X@W)[i,u]  +  finalize kcl ----------------
// grid 512 (8 b x 64 i-chunks of 32), block 256 = 4 waves; wave w owns u in [w*32, w*32+32).
__global__ __launch_bounds__(256, 2)
void gcn_xwT(const float* __restrict__ X, const unsigned short* __restrict__ WTb,
             const float* __restrict__ partial, const float* __restrict__ pptr,
             float* __restrict__ kcl, unsigned short* __restrict__ YT) {
  __shared__ __align__(16) unsigned short Wl[128 * 128];  // [u][k] swizzled, 32 KB
  __shared__ __align__(16) unsigned short Xl[32 * 128];   // [i][k] swizzled, 8 KB
  __shared__ float red[8][33];
  __shared__ float kct[32];

  const int t = threadIdx.x;
  const int lane = t & 63;
  const int wid = t >> 6;
  const int b = blockIdx.x >> 6;
  const int i0 = (blockIdx.x & 63) << 5;

  // stage WT (global_load_lds, linear dest, inverse-swizzled source)
  #pragma unroll
  for (int rnd = 0; rnd < 8; ++rnd) {
    const int u = rnd * 16 + (t >> 4);
    const int c16 = (t & 15) ^ (u & 7);
    async_load16(WTb + u * 128 + c16 * 8, &Wl[rnd * 2048 + (t & ~63) * 8]);
  }
  // stage X tile (reg-staged fp32->bf16, swizzled ds_write)
  {
    const int r = t >> 3;
    const float* xp = X + ((size_t)b * N + i0 + r) * F + (t & 7) * 8;
    #pragma unroll
    for (int h = 0; h < 2; ++h) {
      float4 v0 = *(const float4*)(xp + h * 64);
      float4 v1 = *(const float4*)(xp + h * 64 + 4);
      us8 w;
      w[0] = f2bf(v0.x); w[1] = f2bf(v0.y); w[2] = f2bf(v0.z); w[3] = f2bf(v0.w);
      w[4] = f2bf(v1.x); w[5] = f2bf(v1.y); w[6] = f2bf(v1.z); w[7] = f2bf(v1.w);
      const int slot = (t & 7) + h * 8;
      *(us8*)&Xl[r * 128 + ((slot ^ (r & 7)) * 8)] = w;
    }
  }
  // column-sum finalize for this block's 32 i-values
  {
    const int col = t & 31;
    const int grp = t >> 5;
    float s = 0.f;
    #pragma unroll
    for (int rr = 0; rr < 8; ++rr)
      s += partial[((size_t)b * 64 + grp * 8 + rr) * N + i0 + col];
    red[grp][col] = s;
  }
  __syncthreads();
  if (t < 32) {
    float s = 0.f;
    #pragma unroll
    for (int g = 0; g < 8; ++g) s += red[g][t];
    const float sp = 1.0f / (1.0f + __expf(-pptr[0]));
    const float k = sp + (1.0f - sp) * s;
    float rv = rsqrtf(sqrtf(k));            // k^(-0.25)
    if (isinf(rv)) rv = 0.f;
    kct[t] = rv;
    kcl[b * N + i0 + t] = rv;
  }
  __syncthreads();

  f32x4 acc[2][2];
  #pragma unroll
  for (int a = 0; a < 2; ++a)
    #pragma unroll
    for (int c = 0; c < 2; ++c) { f32x4 z = {0.f, 0.f, 0.f, 0.f}; acc[a][c] = z; }

  const int u0 = wid * 32;
  #pragma unroll
  for (int kc = 0; kc < 4; ++kc) {
    bf16x8 af[2], bfv[2];
    #pragma unroll
    for (int ut = 0; ut < 2; ++ut) {
      const int u = u0 + ut * 16 + (lane & 15);
      const int sl = ((kc * 4 + (lane >> 4)) ^ (u & 7)) * 8;
      af[ut] = *(const bf16x8*)&Wl[u * 128 + sl];
    }
    #pragma unroll
    for (int it = 0; it < 2; ++it) {
      const int rr = it * 16 + (lane & 15);
      const int sl = ((kc * 4 + (lane >> 4)) ^ (rr & 7)) * 8;
      bfv[it] = *(const bf16x8*)&Xl[rr * 128 + sl];
    }
    #pragma unroll
    for (int ut = 0; ut < 2; ++ut)
      #pragma unroll
      for (int it = 0; it < 2; ++it)
        acc[ut][it] = __builtin_amdgcn_mfma_f32_16x16x32_bf16(af[ut], bfv[it], acc[ut][it], 0, 0, 0);
  }

  // epilogue: scale by kc[b,i], write YT[b,u,i] (coalesced in i)
  #pragma unroll
  for (int ut = 0; ut < 2; ++ut) {
    #pragma unroll
    for (int it = 0; it < 2; ++it) {
      const int ic = it * 16 + (lane & 15);
      const float kv = kct[ic];
      #pragma unroll
      for (int rg = 0; rg < 4; ++rg) {
        const int u = u0 + ut * 16 + (lane >> 4) * 4 + rg;
        YT[(size_t)b * UDIM * N + (size_t)u * N + i0 + ic] = f2bf(acc[ut][it][rg] * kv);
      }
    }
  }
}

// ---------------- kernel 3: out = relu(kc_i * Abf @ Y + bias) ----------------
// grid 512, block 256 = 4 waves (2x2). XCD-aware: b = bid&7 (batch pinned to XCD).
// 3-buffer counted-vmcnt pipeline: 5 load-instructions per k-tile, 2 tiles in flight.
__global__ __launch_bounds__(256, 2)
void gcn_gemm(const unsigned short* __restrict__ Abf, const unsigned short* __restrict__ YT,
              const float* __restrict__ kcl, const float* __restrict__ bias,
              float* __restrict__ out) {
  __shared__ __align__(16) unsigned short Abuf[3][32 * 64];   // 4 KB each, swizzled
  __shared__ __align__(16) unsigned short Ybuf[3][128 * 64];  // 16 KB each, swizzled

  const int t = threadIdx.x;
  const int lane = t & 63;
  const int wid = t >> 6;
  const int wr = wid >> 1;
  const int wc = wid & 1;

  const int bid = blockIdx.x;
  const int b = bid & 7;             // XCD-aware: batch b -> XCD b
  const int i0 = (bid >> 3) << 5;

  const int r = t >> 3;        // A-staging row within tile (0..31)
  const int c8 = t & 7;        // A-staging 8-elem column chunk
  const unsigned short* Ab = Abf + (size_t)b * N * N + (size_t)(i0 + r) * N + ((c8 ^ (r & 7)) * 8);
  const unsigned short* YTb = YT + (size_t)b * UDIM * N;

  const int a_wavebase = (t & ~63) * 8;   // ushort offset of wave's 1KB LDS slice
  const int y_u = t >> 3;                 // + rnd*32
  const int y_wavebase = (t & ~63) * 8;

  f32x4 acc[4];
  #pragma unroll
  for (int i = 0; i < 4; ++i) { f32x4 z = {0.f, 0.f, 0.f, 0.f}; acc[i] = z; }

  auto issue = [&](int kt, int buf) {
    const int k0 = kt * 64;
    #pragma unroll
    for (int rnd = 0; rnd < 4; ++rnd) {
      const int u = rnd * 32 + y_u;
      const int c16 = (t & 7) ^ (u & 7);
      async_load16(YTb + (size_t)u * N + k0 + c16 * 8, &Ybuf[buf][rnd * 2048 + y_wavebase]);
    }
    async_load16(Ab + k0, &Abuf[buf][a_wavebase]);
  };

  auto compute = [&](int cur) {
    #pragma unroll
    for (int kk = 0; kk < 2; ++kk) {
      const int ar = 16 * wr + (lane & 15);
      const int as = ((kk * 4 + (lane >> 4)) ^ (ar & 7)) * 8;
      bf16x8 af = *(const bf16x8*)&Abuf[cur][ar * 64 + as];
      #pragma unroll
      for (int ut = 0; ut < 4; ++ut) {
        const int u = 64 * wc + ut * 16 + (lane & 15);
        const int bs = ((kk * 4 + (lane >> 4)) ^ (u & 7)) * 8;
        bf16x8 bfv = *(const bf16x8*)&Ybuf[cur][u * 64 + bs];
        acc[ut] = __builtin_amdgcn_mfma_f32_16x16x32_bf16(af, bfv, acc[ut], 0, 0, 0);
      }
    }
  };

  // prologue: 2 tiles in flight
  issue(0, 0);
  issue(1, 1);

  #pragma unroll 1
  for (int kt0 = 0; kt0 < 30; kt0 += 3) {
    asm volatile("s_waitcnt vmcnt(5)" ::: "memory");
    __builtin_amdgcn_s_barrier();
    __builtin_amdgcn_sched_barrier(0);
    issue(kt0 + 2, 2);
    compute(0);

    asm volatile("s_waitcnt vmcnt(5)" ::: "memory");
    __builtin_amdgcn_s_barrier();
    __builtin_amdgcn_sched_barrier(0);
    issue(kt0 + 3, 0);
    compute(1);

    asm volatile("s_waitcnt vmcnt(5)" ::: "memory");
    __builtin_amdgcn_s_barrier();
    __builtin_amdgcn_sched_barrier(0);
    issue(kt0 + 4, 1);
    compute(2);
  }
  // kt = 30 (buf 0), no new issue
  asm volatile("s_waitcnt vmcnt(5)" ::: "memory");
  __builtin_amdgcn_s_barrier();
  __builtin_amdgcn_sched_barrier(0);
  compute(0);
  // kt = 31 (buf 1), drain
  asm volatile("s_waitcnt vmcnt(0)" ::: "memory");
  __builtin_amdgcn_s_barrier();
  __builtin_amdgcn_sched_barrier(0);
  compute(1);

  // epilogue: row scale + bias + relu
  const int irow = i0 + 16 * wr + (lane >> 4) * 4;
  #pragma unroll
  for (int ut = 0; ut < 4; ++ut) {
    const int u = 64 * wc + ut * 16 + (lane & 15);
    const float bv = bias[u];
    #pragma unroll
    for (int rg = 0; rg < 4; ++rg) {
      const int i = irow + rg;
      const float kv = kcl[b * N + i];
      float vv = kv * acc[ut][rg] + bv;
      out[((size_t)b * N + i) * UDIM + u] = vv > 0.f ? vv : 0.f;
    }
  }
}

extern "C" void kernel_launch(void* const* d_in, const int* in_sizes, int n_in,
                              void* d_out, int out_size, void* d_ws, size_t ws_size,
                              hipStream_t stream) {
  (void)in_sizes; (void)n_in; (void)out_size; (void)ws_size;
  const float* A    = (const float*)d_in[0];
  const float* X    = (const float*)d_in[1];
  const float* W    = (const float*)d_in[2];
  const float* bias = (const float*)d_in[3];
  const float* p    = (const float*)d_in[4];
  const float* q    = (const float*)d_in[5];
  float* out = (float*)d_out;

  char* ws = (char*)d_ws;
  float* partial      = (float*)ws;                                   // 8*64*2048*4 = 4 MB
  float* kcl          = (float*)(ws + 4194304);                       // 64 KB
  unsigned short* WTb = (unsigned short*)(ws + 4194304 + 65536);      // 32 KB
  unsigned short* YT  = (unsigned short*)(ws + 4292608);              // 4 MB
  unsigned short* Abf = (unsigned short*)(ws + 4292608 + 4194304);    // 64 MB

  gcn_colsum_conv<<<dim3(2, 64, 8), dim3(256), 0, stream>>>(A, q, W, partial, Abf, WTb);
  gcn_xwT<<<dim3(512), dim3(256), 0, stream>>>(X, WTb, partial, p, kcl, YT);
  gcn_gemm<<<dim3(512), dim3(256), 0, stream>>>(Abf, YT, kcl, bias, out);
}

// Round 4
// 62.154 us; speedup vs baseline: 1.3071x; 1.0153x over previous
//
#include <hip/hip_runtime.h>
#include <stdint.h>

#define N 2048
#define F 128
#define UDIM 128

typedef __attribute__((ext_vector_type(8))) __bf16 bf16x8;
typedef __attribute__((ext_vector_type(8))) unsigned short us8;
typedef __attribute__((ext_vector_type(4))) float f32x4;

__device__ __forceinline__ unsigned short f2bf(float f) {
  union { float f; uint32_t u; } v; v.f = f;
  uint32_t u = v.u;
  return (unsigned short)((u + 0x7FFFu + ((u >> 16) & 1u)) >> 16);
}
__device__ __forceinline__ float bf2f(unsigned short u) {
  union { uint32_t u; float f; } v; v.u = ((uint32_t)u) << 16; return v.f;
}

__device__ __forceinline__ void async_load16(const void* g, void* l) {
  typedef const __attribute__((address_space(1))) uint32_t* gp_t;
  typedef __attribute__((address_space(3))) uint32_t* lp_t;
  __builtin_amdgcn_global_load_lds((gp_t)(uintptr_t)g, (lp_t)(uint32_t)(uintptr_t)l, 16, 0, 0);
}

// ---------------- kernel 1: pure column-sum partials + W -> WTb ----------------
// grid (2, 64, 8), block 256, 32 rows per block. partial[b][rc][j]. 134 MB stream.
__global__ __launch_bounds__(256)
void gcn_colsum(const float* __restrict__ A, const float* __restrict__ W,
                float* __restrict__ partial, unsigned short* __restrict__ WTb) {
  const int b = blockIdx.z;
  const int rc = blockIdx.y;
  const int j = blockIdx.x * 1024 + threadIdx.x * 4;
  const float* ap = A + (size_t)b * N * N + (size_t)rc * 32 * N + j;
  float s0 = 0.f, s1 = 0.f, s2 = 0.f, s3 = 0.f;
  #pragma unroll 4
  for (int rr = 0; rr < 32; ++rr) {
    float4 v = *(const float4*)(ap + (size_t)rr * N);
    s0 += v.x; s1 += v.y; s2 += v.z; s3 += v.w;
  }
  float4 s; s.x = s0; s.y = s1; s.z = s2; s.w = s3;
  *(float4*)&partial[((size_t)b * 64 + rc) * N + j] = s;

  // 2 designated blocks also build WT_bf[u][k] (16384 elems, coalesced W read)
  if (blockIdx.y == 0 && blockIdx.z == 0) {
    #pragma unroll 4
    for (int it = 0; it < 32; ++it) {
      const int flat = it * 512 + blockIdx.x * 256 + threadIdx.x;
      const int k_ = flat >> 7;
      const int u = flat & 127;
      WTb[u * 128 + k_] = f2bf(W[flat]);
    }
  }
}

// ---------------- kernel 2: YT[b,u,i] = kc[b,i]*(X@W)[i,u]  +  finalize kcl ----------------
__global__ __launch_bounds__(256, 2)
void gcn_xwT(const float* __restrict__ X, const unsigned short* __restrict__ WTb,
             const float* __restrict__ partial, const float* __restrict__ pptr,
             float* __restrict__ kcl, unsigned short* __restrict__ YT) {
  __shared__ __align__(16) unsigned short Wl[128 * 128];  // [u][k] swizzled, 32 KB
  __shared__ __align__(16) unsigned short Xl[32 * 128];   // [i][k] swizzled, 8 KB
  __shared__ float red[8][33];
  __shared__ float kct[32];

  const int t = threadIdx.x;
  const int lane = t & 63;
  const int wid = t >> 6;
  const int b = blockIdx.x >> 6;
  const int i0 = (blockIdx.x & 63) << 5;

  #pragma unroll
  for (int rnd = 0; rnd < 8; ++rnd) {
    const int u = rnd * 16 + (t >> 4);
    const int c16 = (t & 15) ^ (u & 7);
    async_load16(WTb + u * 128 + c16 * 8, &Wl[rnd * 2048 + (t & ~63) * 8]);
  }
  {
    const int r = t >> 3;
    const float* xp = X + ((size_t)b * N + i0 + r) * F + (t & 7) * 8;
    #pragma unroll
    for (int h = 0; h < 2; ++h) {
      float4 v0 = *(const float4*)(xp + h * 64);
      float4 v1 = *(const float4*)(xp + h * 64 + 4);
      us8 w;
      w[0] = f2bf(v0.x); w[1] = f2bf(v0.y); w[2] = f2bf(v0.z); w[3] = f2bf(v0.w);
      w[4] = f2bf(v1.x); w[5] = f2bf(v1.y); w[6] = f2bf(v1.z); w[7] = f2bf(v1.w);
      const int slot = (t & 7) + h * 8;
      *(us8*)&Xl[r * 128 + ((slot ^ (r & 7)) * 8)] = w;
    }
  }
  {
    const int col = t & 31;
    const int grp = t >> 5;
    float s = 0.f;
    #pragma unroll
    for (int rr = 0; rr < 8; ++rr)
      s += partial[((size_t)b * 64 + grp * 8 + rr) * N + i0 + col];
    red[grp][col] = s;
  }
  __syncthreads();
  if (t < 32) {
    float s = 0.f;
    #pragma unroll
    for (int g = 0; g < 8; ++g) s += red[g][t];
    const float sp = 1.0f / (1.0f + __expf(-pptr[0]));
    const float k = sp + (1.0f - sp) * s;
    float rv = rsqrtf(sqrtf(k));            // k^(-0.25)
    if (isinf(rv)) rv = 0.f;
    kct[t] = rv;
    kcl[b * N + i0 + t] = rv;
  }
  __syncthreads();

  f32x4 acc[2][2];
  #pragma unroll
  for (int a = 0; a < 2; ++a)
    #pragma unroll
    for (int c = 0; c < 2; ++c) { f32x4 z = {0.f, 0.f, 0.f, 0.f}; acc[a][c] = z; }

  const int u0 = wid * 32;
  #pragma unroll
  for (int kc = 0; kc < 4; ++kc) {
    bf16x8 af[2], bfv[2];
    #pragma unroll
    for (int ut = 0; ut < 2; ++ut) {
      const int u = u0 + ut * 16 + (lane & 15);
      const int sl = ((kc * 4 + (lane >> 4)) ^ (u & 7)) * 8;
      af[ut] = *(const bf16x8*)&Wl[u * 128 + sl];
    }
    #pragma unroll
    for (int it = 0; it < 2; ++it) {
      const int rr = it * 16 + (lane & 15);
      const int sl = ((kc * 4 + (lane >> 4)) ^ (rr & 7)) * 8;
      bfv[it] = *(const bf16x8*)&Xl[rr * 128 + sl];
    }
    #pragma unroll
    for (int ut = 0; ut < 2; ++ut)
      #pragma unroll
      for (int it = 0; it < 2; ++it)
        acc[ut][it] = __builtin_amdgcn_mfma_f32_16x16x32_bf16(af[ut], bfv[it], acc[ut][it], 0, 0, 0);
  }

  #pragma unroll
  for (int ut = 0; ut < 2; ++ut) {
    #pragma unroll
    for (int it = 0; it < 2; ++it) {
      const int ic = it * 16 + (lane & 15);
      const float kv = kct[ic];
      #pragma unroll
      for (int rg = 0; rg < 4; ++rg) {
        const int u = u0 + ut * 16 + (lane >> 4) * 4 + rg;
        YT[(size_t)b * UDIM * N + (size_t)u * N + i0 + ic] = f2bf(acc[ut][it][rg] * kv);
      }
    }
  }
}

// ---------------- kernel 3: out = relu(kc_i * (A @ Y + qs*Y_i) + bias) ----------------
// A read fp32 (L3-resident after pass 1), converted to bf16 in-register during staging.
// 3-buffer pipeline: group(g) = [A-regs x2, Y-lds x4]; vmcnt(4) retires A(kt+1) + Y(kt).
__global__ __launch_bounds__(256, 2)
void gcn_gemm(const float* __restrict__ A, const unsigned short* __restrict__ YT,
              const float* __restrict__ kcl, const float* __restrict__ bias,
              const float* __restrict__ qptr, float* __restrict__ out) {
  __shared__ __align__(16) unsigned short Abuf[3][32 * 64];   // 4 KB each, swizzled
  __shared__ __align__(16) unsigned short Ybuf[3][128 * 64];  // 16 KB each, swizzled

  const int t = threadIdx.x;
  const int lane = t & 63;
  const int wid = t >> 6;
  const int wr = wid >> 1;
  const int wc = wid & 1;

  const int bid = blockIdx.x;
  const int b = bid & 7;             // XCD-aware: batch b -> XCD b
  const int i0 = (bid >> 3) << 5;

  const float qs = 1.0f / (1.0f + __expf(-qptr[0]));

  const int r = t >> 3;              // A-staging row within tile (0..31)
  const int c8 = t & 7;              // A-staging 8-float column chunk
  const float* Ap = A + (size_t)b * N * N + (size_t)(i0 + r) * N + c8 * 8;
  const unsigned short* YTb = YT + (size_t)b * UDIM * N;

  const int a_woff = r * 64 + ((c8 ^ (r & 7)) * 8);   // swizzled ds_write slot (ushort)
  const int y_u = t >> 3;
  const int y_wavebase = (t & ~63) * 8;

  f32x4 acc[4];
  #pragma unroll
  for (int i = 0; i < 4; ++i) { f32x4 z = {0.f, 0.f, 0.f, 0.f}; acc[i] = z; }

  float4 ar0, ar1;   // in-flight A fp32 regs (one tile)

  auto issueA = [&](int kt) {
    ar0 = *(const float4*)(Ap + kt * 64);
    ar1 = *(const float4*)(Ap + kt * 64 + 4);
  };
  auto issueY = [&](int kt, int buf) {
    const int k0 = kt * 64;
    #pragma unroll
    for (int rnd = 0; rnd < 4; ++rnd) {
      const int u = rnd * 32 + y_u;
      const int c16 = (t & 7) ^ (u & 7);
      async_load16(YTb + (size_t)u * N + k0 + c16 * 8, &Ybuf[buf][rnd * 2048 + y_wavebase]);
    }
  };
  auto convertA = [&](int buf) {
    us8 w;
    w[0] = f2bf(ar0.x); w[1] = f2bf(ar0.y); w[2] = f2bf(ar0.z); w[3] = f2bf(ar0.w);
    w[4] = f2bf(ar1.x); w[5] = f2bf(ar1.y); w[6] = f2bf(ar1.z); w[7] = f2bf(ar1.w);
    *(us8*)&Abuf[buf][a_woff] = w;
  };
  auto compute = [&](int cur) {
    #pragma unroll
    for (int kk = 0; kk < 2; ++kk) {
      const int ar = 16 * wr + (lane & 15);
      const int as = ((kk * 4 + (lane >> 4)) ^ (ar & 7)) * 8;
      bf16x8 af = *(const bf16x8*)&Abuf[cur][ar * 64 + as];
      #pragma unroll
      for (int ut = 0; ut < 4; ++ut) {
        const int u = 64 * wc + ut * 16 + (lane & 15);
        const int bs = ((kk * 4 + (lane >> 4)) ^ (u & 7)) * 8;
        bf16x8 bfv = *(const bf16x8*)&Ybuf[cur][u * 64 + bs];
        acc[ut] = __builtin_amdgcn_mfma_f32_16x16x32_bf16(af, bfv, acc[ut], 0, 0, 0);
      }
    }
  };

#define STEP(KT, CUR, NXT, ISS)                                  \
  {                                                              \
    asm volatile("s_waitcnt vmcnt(4)" ::: "memory");             \
    convertA(NXT);                                               \
    asm volatile("s_waitcnt lgkmcnt(0)" ::: "memory");           \
    __builtin_amdgcn_s_barrier();                                \
    __builtin_amdgcn_sched_barrier(0);                           \
    issueA((KT) + 2);                                            \
    __builtin_amdgcn_sched_barrier(0);                           \
    issueY((KT) + 2, (ISS));                                     \
    __builtin_amdgcn_sched_barrier(0);                           \
    compute(CUR);                                                \
  }

  // prologue
  issueA(0);
  __builtin_amdgcn_sched_barrier(0);
  issueY(0, 0);
  __builtin_amdgcn_sched_barrier(0);
  asm volatile("s_waitcnt vmcnt(4)" ::: "memory");   // A(0) regs ready
  convertA(0);
  __builtin_amdgcn_sched_barrier(0);
  issueA(1);
  __builtin_amdgcn_sched_barrier(0);
  issueY(1, 1);
  __builtin_amdgcn_sched_barrier(0);

  #pragma unroll 1
  for (int kt0 = 0; kt0 < 30; kt0 += 3) {
    STEP(kt0,     0, 1, 2);
    STEP(kt0 + 1, 1, 2, 0);
    STEP(kt0 + 2, 2, 0, 1);
  }
#undef STEP

  // kt = 30: convert A(31), no new issue
  asm volatile("s_waitcnt vmcnt(4)" ::: "memory");
  convertA(1);
  asm volatile("s_waitcnt lgkmcnt(0)" ::: "memory");
  __builtin_amdgcn_s_barrier();
  __builtin_amdgcn_sched_barrier(0);
  compute(0);
  // kt = 31: drain
  asm volatile("s_waitcnt vmcnt(0)" ::: "memory");
  __builtin_amdgcn_s_barrier();
  __builtin_amdgcn_sched_barrier(0);
  compute(1);

  // epilogue: diagonal qs*Y_i + row scale + bias + relu
  const int irow = i0 + 16 * wr + (lane >> 4) * 4;
  #pragma unroll
  for (int ut = 0; ut < 4; ++ut) {
    const int u = 64 * wc + ut * 16 + (lane & 15);
    const float bv = bias[u];
    #pragma unroll
    for (int rg = 0; rg < 4; ++rg) {
      const int i = irow + rg;
      const float yv = bf2f(YTb[(size_t)u * N + i]);
      const float kv = kcl[b * N + i];
      float vv = kv * (acc[ut][rg] + qs * yv) + bv;
      out[((size_t)b * N + i) * UDIM + u] = vv > 0.f ? vv : 0.f;
    }
  }
}

extern "C" void kernel_launch(void* const* d_in, const int* in_sizes, int n_in,
                              void* d_out, int out_size, void* d_ws, size_t ws_size,
                              hipStream_t stream) {
  (void)in_sizes; (void)n_in; (void)out_size; (void)ws_size;
  const float* A    = (const float*)d_in[0];
  const float* X    = (const float*)d_in[1];
  const float* W    = (const float*)d_in[2];
  const float* bias = (const float*)d_in[3];
  const float* p    = (const float*)d_in[4];
  const float* q    = (const float*)d_in[5];
  float* out = (float*)d_out;

  char* ws = (char*)d_ws;
  float* partial      = (float*)ws;                                   // 8*64*2048*4 = 4 MB
  float* kcl          = (float*)(ws + 4194304);                       // 64 KB
  unsigned short* WTb = (unsigned short*)(ws + 4194304 + 65536);      // 32 KB
  unsigned short* YT  = (unsigned short*)(ws + 4292608);              // 4 MB

  gcn_colsum<<<dim3(2, 64, 8), dim3(256), 0, stream>>>(A, W, partial, WTb);
  gcn_xwT<<<dim3(512), dim3(256), 0, stream>>>(X, WTb, partial, p, kcl, YT);
  gcn_gemm<<<dim3(512), dim3(256), 0, stream>>>(A, YT, kcl, bias, q, out);
}

// Round 5
// 58.859 us; speedup vs baseline: 1.3803x; 1.0560x over previous
//
#include <hip/hip_runtime.h>
#include <stdint.h>

#define N 2048
#define F 128
#define UDIM 128

typedef __attribute__((ext_vector_type(8))) __bf16 bf16x8;
typedef __attribute__((ext_vector_type(8))) unsigned short us8;
typedef __attribute__((ext_vector_type(4))) float f32x4;

__device__ __forceinline__ unsigned short f2bf(float f) {
  union { float f; uint32_t u; } v; v.f = f;
  uint32_t u = v.u;
  return (unsigned short)((u + 0x7FFFu + ((u >> 16) & 1u)) >> 16);
}
__device__ __forceinline__ float bf2f(unsigned short u) {
  union { uint32_t u; float f; } v; v.u = ((uint32_t)u) << 16; return v.f;
}
// packed f32x2 -> bf16x2 (RNE, single instruction)
__device__ __forceinline__ uint32_t cvtpk(float lo, float hi) {
  uint32_t r;
  asm("v_cvt_pk_bf16_f32 %0, %1, %2" : "=v"(r) : "v"(lo), "v"(hi));
  return r;
}

__device__ __forceinline__ void async_load16(const void* g, void* l) {
  typedef const __attribute__((address_space(1))) uint32_t* gp_t;
  typedef __attribute__((address_space(3))) uint32_t* lp_t;
  __builtin_amdgcn_global_load_lds((gp_t)(uintptr_t)g, (lp_t)(uint32_t)(uintptr_t)l, 16, 0, 0);
}

// ================ kernel 1: [colsum blocks 0..1023] + [Z=(X@W)^T blocks 1024..1535] ================
__global__ __launch_bounds__(256, 4)
void gcn_pass1(const float* __restrict__ A, const float* __restrict__ X,
               const float* __restrict__ W, float* __restrict__ partial,
               unsigned short* __restrict__ Z) {
  __shared__ __align__(16) unsigned short Wl[128 * 128];  // [u][k] swizzled (xwT role only)
  __shared__ __align__(16) unsigned short Xl[32 * 128];   // [i][k] swizzled

  const int bid = blockIdx.x;
  const int t = threadIdx.x;

  if (bid < 1024) {
    // ---- colsum role: partial[b][rc][j], 32 rows per block ----
    const int b = bid >> 7;
    const int rc = (bid >> 1) & 63;
    const int j = (bid & 1) * 1024 + t * 4;
    const float* ap = A + (size_t)b * N * N + (size_t)rc * 32 * N + j;
    float s0 = 0.f, s1 = 0.f, s2 = 0.f, s3 = 0.f;
    #pragma unroll 4
    for (int rr = 0; rr < 32; ++rr) {
      float4 v = *(const float4*)(ap + (size_t)rr * N);
      s0 += v.x; s1 += v.y; s2 += v.z; s3 += v.w;
    }
    float4 s; s.x = s0; s.y = s1; s.z = s2; s.w = s3;
    *(float4*)&partial[((size_t)b * 64 + rc) * N + j] = s;
    return;
  }

  // ---- xwT role: Z[b,u,i] = (X@W)[i,u] (unscaled), computed transposed ----
  const int zid = bid - 1024;
  const int lane = t & 63;
  const int wid = t >> 6;
  const int b = zid >> 6;
  const int i0 = (zid & 63) << 5;

  // stage W^T into Wl[u][k] (swizzled): thread owns u=t&127, k-half = t>>7
  {
    const int u = t & 127;
    const int khalf = t >> 7;
    #pragma unroll
    for (int g = 0; g < 8; ++g) {
      const int k0 = khalf * 64 + g * 8;
      float v[8];
      #pragma unroll
      for (int e = 0; e < 8; ++e) v[e] = W[(size_t)(k0 + e) * 128 + u];
      uint4 w;
      w.x = cvtpk(v[0], v[1]); w.y = cvtpk(v[2], v[3]);
      w.z = cvtpk(v[4], v[5]); w.w = cvtpk(v[6], v[7]);
      const int slot = khalf * 8 + g;
      *(uint4*)&Wl[u * 128 + ((slot ^ (u & 7)) * 8)] = w;
    }
  }
  // stage X tile (fp32 -> bf16, swizzled)
  {
    const int r = t >> 3;
    const float* xp = X + ((size_t)b * N + i0 + r) * F + (t & 7) * 8;
    #pragma unroll
    for (int h = 0; h < 2; ++h) {
      float4 v0 = *(const float4*)(xp + h * 64);
      float4 v1 = *(const float4*)(xp + h * 64 + 4);
      uint4 w;
      w.x = cvtpk(v0.x, v0.y); w.y = cvtpk(v0.z, v0.w);
      w.z = cvtpk(v1.x, v1.y); w.w = cvtpk(v1.z, v1.w);
      const int slot = (t & 7) + h * 8;
      *(uint4*)&Xl[r * 128 + ((slot ^ (r & 7)) * 8)] = w;
    }
  }
  __syncthreads();

  f32x4 acc[2][2];
  #pragma unroll
  for (int a = 0; a < 2; ++a)
    #pragma unroll
    for (int c = 0; c < 2; ++c) { f32x4 z = {0.f, 0.f, 0.f, 0.f}; acc[a][c] = z; }

  const int u0 = wid * 32;
  #pragma unroll
  for (int kc = 0; kc < 4; ++kc) {
    bf16x8 af[2], bfv[2];
    #pragma unroll
    for (int ut = 0; ut < 2; ++ut) {
      const int u = u0 + ut * 16 + (lane & 15);
      const int sl = ((kc * 4 + (lane >> 4)) ^ (u & 7)) * 8;
      af[ut] = *(const bf16x8*)&Wl[u * 128 + sl];
    }
    #pragma unroll
    for (int it = 0; it < 2; ++it) {
      const int rr = it * 16 + (lane & 15);
      const int sl = ((kc * 4 + (lane >> 4)) ^ (rr & 7)) * 8;
      bfv[it] = *(const bf16x8*)&Xl[rr * 128 + sl];
    }
    #pragma unroll
    for (int ut = 0; ut < 2; ++ut)
      #pragma unroll
      for (int it = 0; it < 2; ++it)
        acc[ut][it] = __builtin_amdgcn_mfma_f32_16x16x32_bf16(af[ut], bfv[it], acc[ut][it], 0, 0, 0);
  }

  #pragma unroll
  for (int ut = 0; ut < 2; ++ut)
    #pragma unroll
    for (int it = 0; it < 2; ++it) {
      const int ic = i0 + it * 16 + (lane & 15);
      #pragma unroll
      for (int rg = 0; rg < 4; ++rg) {
        const int u = u0 + ut * 16 + (lane >> 4) * 4 + rg;
        Z[((size_t)b * UDIM + u) * N + ic] = f2bf(acc[ut][it][rg]);
      }
    }
}

// ================ kernel 2: finalize kcl + YT = kc_i * Z (tiny) ================
// grid 128: b = bid>>4, i-chunk of 128 = (bid&15)*128
__global__ __launch_bounds__(256, 4)
void gcn_scale(const float* __restrict__ partial, const float* __restrict__ pptr,
               const unsigned short* __restrict__ Z, float* __restrict__ kcl,
               unsigned short* __restrict__ YT) {
  __shared__ float red[2][128];
  __shared__ float kct[128];
  const int t = threadIdx.x;
  const int b = blockIdx.x >> 4;
  const int ic = (blockIdx.x & 15) * 128;

  {
    const int i = ic + (t & 127);
    const int half = t >> 7;
    float s = 0.f;
    #pragma unroll 8
    for (int rc = half * 32; rc < half * 32 + 32; ++rc)
      s += partial[((size_t)b * 64 + rc) * N + i];
    red[half][t & 127] = s;
  }
  __syncthreads();
  if (t < 128) {
    const float s = red[0][t] + red[1][t];
    const float sp = 1.0f / (1.0f + __expf(-pptr[0]));
    const float k = sp + (1.0f - sp) * s;
    float rv = rsqrtf(sqrtf(k));            // k^(-0.25)
    if (isinf(rv)) rv = 0.f;
    kct[t] = rv;
    kcl[b * N + ic + t] = rv;
  }
  __syncthreads();

  const int i8 = (t & 15) * 8;
  #pragma unroll
  for (int it = 0; it < 8; ++it) {
    const int u = it * 16 + (t >> 4);
    const size_t off = ((size_t)b * UDIM + u) * N + ic + i8;
    us8 z = *(const us8*)&Z[off];
    float y[8];
    #pragma unroll
    for (int e = 0; e < 8; ++e) y[e] = bf2f(z[e]) * kct[i8 + e];
    uint4 w;
    w.x = cvtpk(y[0], y[1]); w.y = cvtpk(y[2], y[3]);
    w.z = cvtpk(y[4], y[5]); w.w = cvtpk(y[6], y[7]);
    *(uint4*)&YT[off] = w;
  }
}

// ================ kernel 3: out = relu(kc_i * (A @ Y + qs*Y_i) + bias) ================
// 4-buffer pipeline: A fp32 (L3) 2-step reg window; Y 3-step global_load_lds window.
// Steady vmcnt(10) = Y(kt+1)[4] + A(kt+3)[2] + Y(kt+2)[4] left outstanding.
__global__ __launch_bounds__(256, 2)
void gcn_gemm(const float* __restrict__ A, const unsigned short* __restrict__ YT,
              const float* __restrict__ kcl, const float* __restrict__ bias,
              const float* __restrict__ qptr, float* __restrict__ out) {
  __shared__ __align__(16) unsigned short Abuf[4 * 32 * 64];    // 4 x 4 KB, swizzled
  __shared__ __align__(16) unsigned short Ybuf[4 * 128 * 64];   // 4 x 16 KB, swizzled

  const int t = threadIdx.x;
  const int lane = t & 63;
  const int wid = t >> 6;
  const int wr = wid >> 1;
  const int wc = wid & 1;

  const int bid = blockIdx.x;
  const int b = bid & 7;             // XCD-aware: batch b -> XCD b
  const int i0 = (bid >> 3) << 5;

  const float qs = 1.0f / (1.0f + __expf(-qptr[0]));

  const int r = t >> 3;              // A-staging row within tile (0..31)
  const int c8 = t & 7;              // A-staging 8-float column chunk
  const float* Ap = A + (size_t)b * N * N + (size_t)(i0 + r) * N + c8 * 8;
  const unsigned short* YTb = YT + (size_t)b * UDIM * N;

  const int a_woff = r * 64 + ((c8 ^ (r & 7)) * 8);   // swizzled ds_write slot (ushort)
  const int y_u = t >> 3;
  const int y_wavebase = (t & ~63) * 8;

  f32x4 acc[4];
  #pragma unroll
  for (int i = 0; i < 4; ++i) { f32x4 z = {0.f, 0.f, 0.f, 0.f}; acc[i] = z; }

  float4 a0A, a1A, a0B, a1B;   // two in-flight A reg sets

  auto issueY = [&](int kt, int buf) {
    const int k0 = kt * 64;
    #pragma unroll
    for (int rnd = 0; rnd < 4; ++rnd) {
      const int u = rnd * 32 + y_u;
      const int c16 = (t & 7) ^ (u & 7);
      async_load16(YTb + (size_t)u * N + k0 + c16 * 8, &Ybuf[buf * 8192 + rnd * 2048 + y_wavebase]);
    }
  };
  auto compute = [&](int cur) {
    const unsigned short* Ac = Abuf + cur * 2048;
    const unsigned short* Yc = Ybuf + cur * 8192;
    #pragma unroll
    for (int kk = 0; kk < 2; ++kk) {
      const int ar = 16 * wr + (lane & 15);
      const int as = ((kk * 4 + (lane >> 4)) ^ (ar & 7)) * 8;
      bf16x8 af = *(const bf16x8*)&Ac[ar * 64 + as];
      #pragma unroll
      for (int ut = 0; ut < 4; ++ut) {
        const int u = 64 * wc + ut * 16 + (lane & 15);
        const int bs = ((kk * 4 + (lane >> 4)) ^ (u & 7)) * 8;
        bf16x8 bfv = *(const bf16x8*)&Yc[u * 64 + bs];
        acc[ut] = __builtin_amdgcn_mfma_f32_16x16x32_bf16(af, bfv, acc[ut], 0, 0, 0);
      }
    }
  };

#define SB __builtin_amdgcn_sched_barrier(0)
#define ISSUE_A(KT, R0, R1) { R0 = *(const float4*)(Ap + (KT) * 64); R1 = *(const float4*)(Ap + (KT) * 64 + 4); }
#define CVT_A(BUF, R0, R1) { \
    uint4 w; w.x = cvtpk(R0.x, R0.y); w.y = cvtpk(R0.z, R0.w); \
    w.z = cvtpk(R1.x, R1.y); w.w = cvtpk(R1.z, R1.w); \
    *(uint4*)&Abuf[(BUF) * 2048 + a_woff] = w; }

  // ---- prologue (canonical queue order: A before Y at each step) ----
  ISSUE_A(0, a0A, a1A); SB;
  ISSUE_A(1, a0B, a1B); SB;
  issueY(0, 0); SB;
  asm volatile("s_waitcnt vmcnt(6)" ::: "memory");   // retire A(0)
  CVT_A(0, a0A, a1A); SB;
  ISSUE_A(2, a0A, a1A); SB;
  issueY(1, 1); SB;
  asm volatile("s_waitcnt vmcnt(10)" ::: "memory");  // retire A(1)
  CVT_A(1, a0B, a1B); SB;
  ISSUE_A(3, a0B, a1B); SB;
  issueY(2, 2); SB;

#define GSTEP(KT, VM, R0, R1, DO_A, DO_Y)                          \
  {                                                                \
    asm volatile("s_waitcnt vmcnt(" #VM ")" ::: "memory");         \
    CVT_A(((KT) + 2) & 3, R0, R1);                                 \
    asm volatile("s_waitcnt lgkmcnt(0)" ::: "memory");             \
    __builtin_amdgcn_s_barrier(); SB;                              \
    if (DO_A) { ISSUE_A((KT) + 4, R0, R1); } SB;                   \
    if (DO_Y) { issueY((KT) + 3, ((KT) + 3) & 3); } SB;            \
    __builtin_amdgcn_s_setprio(1);                                 \
    compute((KT) & 3);                                             \
    __builtin_amdgcn_s_setprio(0); SB;                             \
  }

  #pragma unroll 1
  for (int kt = 0; kt < 28; kt += 2) {
    GSTEP(kt, 10, a0A, a1A, true, true);
    GSTEP(kt + 1, 10, a0B, a1B, true, true);
  }
  // tail: kt = 28..31
  GSTEP(28, 10, a0A, a1A, false, true);    // issues Y(31); converts A(30)
  GSTEP(29, 8, a0B, a1B, false, false);    // converts A(31)
  // kt = 30
  asm volatile("s_waitcnt vmcnt(4)" ::: "memory");
  __builtin_amdgcn_s_barrier(); SB;
  compute(2);
  // kt = 31
  asm volatile("s_waitcnt vmcnt(0)" ::: "memory");
  __builtin_amdgcn_s_barrier(); SB;
  compute(3);
#undef GSTEP
#undef CVT_A
#undef ISSUE_A
#undef SB

  // epilogue: diagonal qs*Y_i + row scale + bias + relu
  const int irow = i0 + 16 * wr + (lane >> 4) * 4;
  #pragma unroll
  for (int ut = 0; ut < 4; ++ut) {
    const int u = 64 * wc + ut * 16 + (lane & 15);
    const float bv = bias[u];
    #pragma unroll
    for (int rg = 0; rg < 4; ++rg) {
      const int i = irow + rg;
      const float yv = bf2f(YTb[(size_t)u * N + i]);
      const float kv = kcl[b * N + i];
      float vv = kv * (acc[ut][rg] + qs * yv) + bv;
      out[((size_t)b * N + i) * UDIM + u] = vv > 0.f ? vv : 0.f;
    }
  }
}

extern "C" void kernel_launch(void* const* d_in, const int* in_sizes, int n_in,
                              void* d_out, int out_size, void* d_ws, size_t ws_size,
                              hipStream_t stream) {
  (void)in_sizes; (void)n_in; (void)out_size; (void)ws_size;
  const float* A    = (const float*)d_in[0];
  const float* X    = (const float*)d_in[1];
  const float* W    = (const float*)d_in[2];
  const float* bias = (const float*)d_in[3];
  const float* p    = (const float*)d_in[4];
  const float* q    = (const float*)d_in[5];
  float* out = (float*)d_out;

  char* ws = (char*)d_ws;
  float* partial      = (float*)ws;                        // 8*64*2048*4 = 4 MB
  float* kcl          = (float*)(ws + 4194304);            // 64 KB
  unsigned short* Zb  = (unsigned short*)(ws + 4259840);   // 4 MB
  unsigned short* YT  = (unsigned short*)(ws + 8454144);   // 4 MB

  gcn_pass1<<<dim3(1536), dim3(256), 0, stream>>>(A, X, W, partial, Zb);
  gcn_scale<<<dim3(128), dim3(256), 0, stream>>>(partial, p, Zb, kcl, YT);
  gcn_gemm<<<dim3(512), dim3(256), 0, stream>>>(A, YT, kcl, bias, q, out);
}